// Round 1
// baseline (1237.567 us; speedup 1.0000x reference)
//
#include <hip/hip_runtime.h>
#include <math.h>

#define NN 50000
#define EE 800000
#define HIDC 256
#define INCH 320

static __device__ __forceinline__ float4 ld4(const float* p){ return *(const float4*)p; }

// ---------------- node positional MLP: pf = silu(pos@W1+b1)@W2+b2 ----------------
__global__ void node_mlp_kernel(const float* __restrict__ kpts,
                                const float* __restrict__ pts3d,
                                const float* __restrict__ W1, const float* __restrict__ b1,
                                const float* __restrict__ W2, const float* __restrict__ b2,
                                float* __restrict__ pf)
{
  int i = blockIdx.x*blockDim.x + threadIdx.x;
  if (i >= NN) return;
  float u = kpts[2*i]   * (1.0f/1216.0f);
  float v = kpts[2*i+1] * (1.0f/352.0f);
  float d = pts3d[3*i+2];
  float h[32];
#pragma unroll
  for (int j=0;j<32;++j){
    float t = u*W1[j] + v*W1[32+j] + d*W1[64+j] + b1[j];
    h[j] = t / (1.0f + expf(-t));   // silu
  }
  for (int o=0;o<64;o+=4){
    float s0=b2[o], s1=b2[o+1], s2=b2[o+2], s3=b2[o+3];
#pragma unroll
    for (int j=0;j<32;++j){
      float hj = h[j];
      const float* w = W2 + j*64 + o;
      s0 += hj*w[0]; s1 += hj*w[1]; s2 += hj*w[2]; s3 += hj*w[3];
    }
    float4 r = make_float4(s0,s1,s2,s3);
    *(float4*)(pf + (size_t)i*64 + o) = r;
  }
}

// ---------------- fp32 tiled GEMM: C(M,Nt) = A(M,K) @ B(K,Nt) + bias ----------------
// A is split: k<256 from A256 (stride 256), k>=256 from A64 (stride 64).
#define BM 64
#define BN 64
#define BK 32
__global__ __launch_bounds__(256) void gemm_kernel(
    const float* __restrict__ A256, const float* __restrict__ A64,
    const float* __restrict__ B, const float* __restrict__ bias,
    float* __restrict__ C, int M, int Nt, int K)
{
  __shared__ __align__(16) float Als[BK][BM+4];
  __shared__ __align__(16) float Bls[BK][BN+4];
  int tid = threadIdx.x;
  int row0 = blockIdx.x*BM, col0 = blockIdx.y*BN;
  int tx = tid & 15, ty = tid >> 4;
  float acc[4][4] = {};
  int a_m  = tid >> 3;        // 0..31
  int a_k4 = (tid & 7) * 4;   // 0,4,..,28
  int b_k  = tid >> 4;        // 0..15
  int b_n4 = (tid & 15) * 4;  // 0..60

  for (int k0 = 0; k0 < K; k0 += BK) {
#pragma unroll
    for (int h = 0; h < 2; ++h) {
      int m = a_m + h*32;
      int grow = row0 + m;
      int gk = k0 + a_k4;
      float4 av;
      if (grow < M) {
        if (gk < 256) av = ld4(A256 + (size_t)grow*256 + gk);
        else          av = ld4(A64  + (size_t)grow*64  + (gk-256));
      } else av = make_float4(0.f,0.f,0.f,0.f);
      Als[a_k4+0][m]=av.x; Als[a_k4+1][m]=av.y; Als[a_k4+2][m]=av.z; Als[a_k4+3][m]=av.w;
    }
#pragma unroll
    for (int h = 0; h < 2; ++h) {
      int kk = b_k + h*16;
      float4 bv = ld4(B + (size_t)(k0+kk)*Nt + col0 + b_n4);
      *(float4*)&Bls[kk][b_n4] = bv;
    }
    __syncthreads();
#pragma unroll
    for (int kk=0; kk<BK; ++kk) {
      float4 a = *(const float4*)&Als[kk][ty*4];
      float4 b = *(const float4*)&Bls[kk][tx*4];
      acc[0][0]+=a.x*b.x; acc[0][1]+=a.x*b.y; acc[0][2]+=a.x*b.z; acc[0][3]+=a.x*b.w;
      acc[1][0]+=a.y*b.x; acc[1][1]+=a.y*b.y; acc[1][2]+=a.y*b.z; acc[1][3]+=a.y*b.w;
      acc[2][0]+=a.z*b.x; acc[2][1]+=a.z*b.y; acc[2][2]+=a.z*b.z; acc[2][3]+=a.z*b.w;
      acc[3][0]+=a.w*b.x; acc[3][1]+=a.w*b.y; acc[3][2]+=a.w*b.z; acc[3][3]+=a.w*b.w;
    }
    __syncthreads();
  }
  float4 bb = ld4(bias + col0 + tx*4);
#pragma unroll
  for (int i=0;i<4;++i){
    int row = row0 + ty*4 + i;
    if (row < M) {
      float4 o = make_float4(acc[i][0]+bb.x, acc[i][1]+bb.y, acc[i][2]+bb.z, acc[i][3]+bb.w);
      *(float4*)(C + (size_t)row*Nt + col0 + tx*4) = o;
    }
  }
}

// ---------------- CSR build by dst ----------------
__global__ void hist_kernel(const int* __restrict__ ei, int* __restrict__ deg){
  int e = blockIdx.x*blockDim.x + threadIdx.x;
  if (e < EE) atomicAdd(&deg[ei[EE + e]], 1);
}

__global__ void scan_kernel(const int* __restrict__ deg, int* __restrict__ rowptr, int* __restrict__ cursor){
  __shared__ int buf[1024];
  __shared__ int carry_s;
  int t = threadIdx.x;
  if (t == 0) carry_s = 0;
  __syncthreads();
  for (int base = 0; base < NN; base += 1024) {
    int i = base + t;
    int v = (i < NN) ? deg[i] : 0;
    buf[t] = v;
    __syncthreads();
    for (int off = 1; off < 1024; off <<= 1) {
      int other = (t >= off) ? buf[t - off] : 0;
      __syncthreads();
      buf[t] += other;
      __syncthreads();
    }
    int incl = buf[t];
    int carry = carry_s;
    if (i < NN) { int ex = carry + incl - v; rowptr[i] = ex; cursor[i] = ex; }
    __syncthreads();
    if (t == 1023) carry_s = carry + buf[1023];
    __syncthreads();
  }
  if (t == 0) rowptr[NN] = carry_s;
}

__global__ void scatter_kernel(const int* __restrict__ ei, int* __restrict__ cursor, int* __restrict__ eidx){
  int e = blockIdx.x*blockDim.x + threadIdx.x;
  if (e < EE) {
    int dst = ei[EE + e];
    int pos = atomicAdd(&cursor[dst], 1);
    eidx[pos] = e;
  }
}

// ---------------- per-node attention + aggregation + LN/silu/residual ----------------
// one wave (64 lanes) per dst node; lane covers channels [4*lane, 4*lane+4)
__global__ __launch_bounds__(256) void node_attn_kernel(
    const int* __restrict__ ei, const float* __restrict__ kpts,
    const float* __restrict__ xl, const float* __restrict__ xr,
    const float* __restrict__ We, const float* __restrict__ att,
    const float* __restrict__ cbias, const float* __restrict__ gamma,
    const float* __restrict__ beta,
    const int* __restrict__ rowptr, const int* __restrict__ eidx,
    float* __restrict__ ex_buf, float* __restrict__ alpha_out,
    float* __restrict__ inout_id /* in: identity, out: ln(agg)+identity */)
{
  int wid  = threadIdx.x >> 6;
  int lane = threadIdx.x & 63;
  int v = blockIdx.x*4 + wid;
  if (v >= NN) return;
  int c0 = lane*4;
  int head = lane >> 4;

  float4 we0 = ld4(We + c0);
  float4 we1 = ld4(We + 256 + c0);
  float4 we2 = ld4(We + 512 + c0);
  float4 av  = ld4(att + c0);
  float4 xrv = ld4(xr + (size_t)v*256 + c0);
  float du = kpts[2*v]   * (1.0f/1216.0f);
  float dv = kpts[2*v+1] * (1.0f/352.0f);
  int rs = rowptr[v], re = rowptr[v+1];

  float denom = 0.f;
  for (int idx = rs; idx < re; ++idx) {
    int e = eidx[idx];
    int s = ei[e];
    float su = kpts[2*s]   * (1.0f/1216.0f);
    float sv = kpts[2*s+1] * (1.0f/352.0f);
    float ru = du - su, rv = dv - sv;
    float dist = sqrtf(ru*ru + rv*rv);
    float4 xlv = ld4(xl + (size_t)s*256 + c0);
    float m0 = xlv.x + xrv.x + ru*we0.x + rv*we1.x + dist*we2.x;
    float m1 = xlv.y + xrv.y + ru*we0.y + rv*we1.y + dist*we2.y;
    float m2 = xlv.z + xrv.z + ru*we0.z + rv*we1.z + dist*we2.z;
    float m3 = xlv.w + xrv.w + ru*we0.w + rv*we1.w + dist*we2.w;
    m0 = (m0 >= 0.f) ? m0 : 0.2f*m0;
    m1 = (m1 >= 0.f) ? m1 : 0.2f*m1;
    m2 = (m2 >= 0.f) ? m2 : 0.2f*m2;
    m3 = (m3 >= 0.f) ? m3 : 0.2f*m3;
    float p = m0*av.x + m1*av.y + m2*av.z + m3*av.w;
    p += __shfl_xor(p, 1, 64);
    p += __shfl_xor(p, 2, 64);
    p += __shfl_xor(p, 4, 64);
    p += __shfl_xor(p, 8, 64);   // per-16-lane-group head logit (all lanes have it)
    float exv = expf(p);         // unshifted softmax: logits bounded, identical within fp32
    denom += exv;
    if ((lane & 15) == 0) ex_buf[(size_t)e*4 + head] = exv;
  }
  float rdenom = 1.0f / (denom + 1e-16f);

  float4 acc = make_float4(0.f,0.f,0.f,0.f);
  for (int idx = rs; idx < re; ++idx) {
    int e = eidx[idx];
    int s = ei[e];
    float exv = ex_buf[(size_t)e*4 + head];
    float alpha = exv * rdenom;
    if ((lane & 15) == 0) alpha_out[(size_t)e*4 + head] = alpha;
    float4 xlv = ld4(xl + (size_t)s*256 + c0);
    acc.x += xlv.x*alpha; acc.y += xlv.y*alpha; acc.z += xlv.z*alpha; acc.w += xlv.w*alpha;
  }

  float4 cb = ld4(cbias + c0);
  acc.x += cb.x; acc.y += cb.y; acc.z += cb.z; acc.w += cb.w;

  float ps  = acc.x + acc.y + acc.z + acc.w;
  float ps2 = acc.x*acc.x + acc.y*acc.y + acc.z*acc.z + acc.w*acc.w;
#pragma unroll
  for (int off = 1; off < 64; off <<= 1) {
    ps  += __shfl_xor(ps,  off, 64);
    ps2 += __shfl_xor(ps2, off, 64);
  }
  float mu  = ps  * (1.0f/256.0f);
  float var = ps2 * (1.0f/256.0f) - mu*mu;
  float rstd = rsqrtf(var + 1e-5f);
  float4 g  = ld4(gamma + c0);
  float4 b  = ld4(beta  + c0);
  float4 idv = ld4(inout_id + (size_t)v*256 + c0);
  float y0 = (acc.x - mu)*rstd*g.x + b.x;
  float y1 = (acc.y - mu)*rstd*g.y + b.y;
  float y2 = (acc.z - mu)*rstd*g.z + b.z;
  float y3 = (acc.w - mu)*rstd*g.w + b.w;
  y0 = y0 / (1.0f + expf(-y0)) + idv.x;
  y1 = y1 / (1.0f + expf(-y1)) + idv.y;
  y2 = y2 / (1.0f + expf(-y2)) + idv.z;
  y3 = y3 / (1.0f + expf(-y3)) + idv.w;
  *(float4*)(inout_id + (size_t)v*256 + c0) = make_float4(y0,y1,y2,y3);
}

extern "C" void kernel_launch(void* const* d_in, const int* in_sizes, int n_in,
                              void* d_out, int out_size, void* d_ws, size_t ws_size,
                              hipStream_t stream)
{
  const float* x      = (const float*)d_in[0];
  const float* kpts   = (const float*)d_in[1];
  const float* pts3d  = (const float*)d_in[2];
  const int*   ei     = (const int*)d_in[3];
  const float* W1     = (const float*)d_in[4];
  const float* b1     = (const float*)d_in[5];
  const float* W2     = (const float*)d_in[6];
  const float* b2     = (const float*)d_in[7];
  const float* Wres   = (const float*)d_in[8];
  const float* bres   = (const float*)d_in[9];
  const float* Wl     = (const float*)d_in[10];
  const float* bl     = (const float*)d_in[11];
  const float* Wr     = (const float*)d_in[12];
  const float* br     = (const float*)d_in[13];
  const float* We     = (const float*)d_in[14];
  const float* att    = (const float*)d_in[15];
  const float* cbias  = (const float*)d_in[16];
  const float* gamma  = (const float*)d_in[17];
  const float* beta   = (const float*)d_in[18];
  const float* Wp     = (const float*)d_in[19];
  const float* bp     = (const float*)d_in[20];

  float* out       = (float*)d_out;
  float* alpha_out = out + (size_t)NN*HIDC;

  // workspace layout (elements of float):
  //   identity: 12.8M | x_l: 12.8M | x_r: 12.8M | pf: 3.2M | ex: 3.2M | ints
  float* wsf      = (float*)d_ws;
  float* identity = wsf;
  float* x_l      = wsf + 12800000;
  float* x_r      = wsf + 25600000;
  float* pf       = wsf + 38400000;
  float* exb      = wsf + 41600000;
  int*   deg      = (int*)(wsf + 44800000);
  int*   rowptr   = deg + NN;
  int*   cursor   = rowptr + NN + 1;
  int*   eidx     = cursor + NN;

  node_mlp_kernel<<<(NN+255)/256, 256, 0, stream>>>(kpts, pts3d, W1, b1, W2, b2, pf);

  dim3 ggrid((NN+BM-1)/BM, HIDC/BN);
  gemm_kernel<<<ggrid, 256, 0, stream>>>(x, pf, Wres, bres, identity, NN, HIDC, INCH);
  gemm_kernel<<<ggrid, 256, 0, stream>>>(x, pf, Wl,   bl,   x_l,      NN, HIDC, INCH);
  gemm_kernel<<<ggrid, 256, 0, stream>>>(x, pf, Wr,   br,   x_r,      NN, HIDC, INCH);

  hipMemsetAsync(deg, 0, NN*sizeof(int), stream);
  hist_kernel<<<(EE+255)/256, 256, 0, stream>>>(ei, deg);
  scan_kernel<<<1, 1024, 0, stream>>>(deg, rowptr, cursor);
  scatter_kernel<<<(EE+255)/256, 256, 0, stream>>>(ei, cursor, eidx);

  node_attn_kernel<<<(NN+3)/4, 256, 0, stream>>>(ei, kpts, x_l, x_r, We, att,
                                                 cbias, gamma, beta,
                                                 rowptr, eidx, exb, alpha_out, identity);

  gemm_kernel<<<ggrid, 256, 0, stream>>>(identity, pf, Wp, bp, out, NN, HIDC, HIDC);
}

// Round 2
// 729.909 us; speedup vs baseline: 1.6955x; 1.6955x over previous
//
#include <hip/hip_runtime.h>
#include <math.h>

#define NN 50000
#define NPAD 50048
#define EE 800000
#define HIDC 256
#define INCH 320

typedef __attribute__((ext_vector_type(8))) short bf16x8;
typedef __attribute__((ext_vector_type(4))) float f32x4;

static __device__ __forceinline__ float4 ld4(const float* p){ return *(const float4*)p; }

static __device__ __forceinline__ unsigned short f2b(float f){
  union { float f; unsigned u; } v; v.f = f;
  unsigned r = v.u + 0x7fffu + ((v.u >> 16) & 1u);
  return (unsigned short)(r >> 16);
}
static __device__ __forceinline__ float b2f(unsigned short u){
  union { unsigned u; float f; } v; v.u = ((unsigned)u) << 16; return v.f;
}

typedef const __attribute__((address_space(1))) unsigned int* gas_u32;
typedef __attribute__((address_space(3))) unsigned int* las_u32;
static __device__ __forceinline__ void gload_lds16(const void* g, void* l){
  __builtin_amdgcn_global_load_lds((gas_u32)g, (las_u32)l, 16, 0, 0);
}

// ---------------- convert x (fp32 50000x256) into node_x bf16 (NPAD x 320, cols 0..255) ----------------
__global__ void cvt_x_kernel(const float* __restrict__ x, unsigned short* __restrict__ nodex)
{
  int t = blockIdx.x*blockDim.x + threadIdx.x;   // 50000*64 threads
  int row = t >> 6;
  if (row >= NN) return;
  int c4 = (t & 63) * 4;
  float4 v = ld4(x + (size_t)row*256 + c4);
  ushort4 o;
  o.x = f2b(v.x); o.y = f2b(v.y); o.z = f2b(v.z); o.w = f2b(v.w);
  *(ushort4*)(nodex + (size_t)row*320 + c4) = o;
}

// ---------------- node positional MLP: writes bf16 into node_x cols 256..319 ----------------
__global__ void node_mlp_kernel(const float* __restrict__ kpts,
                                const float* __restrict__ pts3d,
                                const float* __restrict__ W1, const float* __restrict__ b1,
                                const float* __restrict__ W2, const float* __restrict__ b2,
                                unsigned short* __restrict__ nodex)
{
  int i = blockIdx.x*blockDim.x + threadIdx.x;
  if (i >= NN) return;
  float u = kpts[2*i]   * (1.0f/1216.0f);
  float v = kpts[2*i+1] * (1.0f/352.0f);
  float d = pts3d[3*i+2];
  float h[32];
#pragma unroll
  for (int j=0;j<32;++j){
    float t = u*W1[j] + v*W1[32+j] + d*W1[64+j] + b1[j];
    h[j] = t / (1.0f + expf(-t));   // silu
  }
  for (int o=0;o<64;o+=4){
    float s0=b2[o], s1=b2[o+1], s2=b2[o+2], s3=b2[o+3];
#pragma unroll
    for (int j=0;j<32;++j){
      float hj = h[j];
      const float* w = W2 + j*64 + o;
      s0 += hj*w[0]; s1 += hj*w[1]; s2 += hj*w[2]; s3 += hj*w[3];
    }
    ushort4 r; r.x=f2b(s0); r.y=f2b(s1); r.z=f2b(s2); r.w=f2b(s3);
    *(ushort4*)(nodex + (size_t)i*320 + 256 + o) = r;
  }
}

// ---------------- convert + transpose weights to bf16 N-major (K contiguous) ----------------
// wt layout: [Wres_T 256x320][Wl_T 256x320][Wr_T 256x320][Wp_T 256x256]
__global__ void cvt_w_kernel(const float* __restrict__ Wres, const float* __restrict__ Wl,
                             const float* __restrict__ Wr,   const float* __restrict__ Wp,
                             unsigned short* __restrict__ wt)
{
  int t = blockIdx.x*blockDim.x + threadIdx.x;   // 311296 threads
  if (t < 245760) {
    int which = t / 81920;
    int rem = t % 81920;
    int n = rem / 320, k = rem % 320;
    const float* W = (which == 0) ? Wres : (which == 1) ? Wl : Wr;
    wt[(size_t)which*81920 + rem] = f2b(W[(size_t)k*256 + n]);
  } else {
    int r = t - 245760;
    int n = r / 256, k = r % 256;
    wt[245760 + r] = f2b(Wp[(size_t)k*256 + n]);
  }
}

// ---------------- bf16 MFMA GEMM: C(M,256) = A(M,K) @ BT(256,K)^T + bias ----------------
// 128x128 tile, BK=32, 4 waves (each 64x64 via 4x4 grid of 16x16x32 MFMAs)
#define GK 32
__global__ __launch_bounds__(256) void mfma_gemm_kernel(
    const unsigned short* __restrict__ A,   // Mpad x K bf16 row-major
    const unsigned short* __restrict__ BT,  // 256 x K bf16 row-major
    const float* __restrict__ bias,         // 256
    float* __restrict__ Cf,                 // fp32 out (or null)
    unsigned short* __restrict__ Cb,        // bf16 out (or null)
    int M, int K)
{
  __shared__ unsigned short Als[128*GK];
  __shared__ unsigned short Bls[128*GK];
  int tid = threadIdx.x;
  int lane = tid & 63, wave = tid >> 6;
  int wm = (wave >> 1) * 64, wn = (wave & 1) * 64;
  int row0 = blockIdx.x * 128, col0 = blockIdx.y * 128;

  f32x4 acc[4][4];
#pragma unroll
  for (int i=0;i<4;++i)
#pragma unroll
    for (int j=0;j<4;++j){ acc[i][j].x=0.f; acc[i][j].y=0.f; acc[i][j].z=0.f; acc[i][j].w=0.f; }

  int fm = lane & 15;
  int fk = (lane >> 4) * 8;

  for (int k0 = 0; k0 < K; k0 += GK) {
#pragma unroll
    for (int it = 0; it < 2; ++it) {
      int seg = it*256 + tid;
      int r = seg >> 2, kb = (seg & 3) * 8;
      // LDS dest: wave-uniform base; lane offset is implicit (lane*16B)
      gload_lds16(A  + (size_t)(row0 + r)*K + k0 + kb, Als + (it*256 + wave*64)*8);
      gload_lds16(BT + (size_t)(col0 + r)*K + k0 + kb, Bls + (it*256 + wave*64)*8);
    }
    __syncthreads();

    bf16x8 af[4], bfr[4];
#pragma unroll
    for (int mi=0; mi<4; ++mi)
      af[mi] = *(const bf16x8*)&Als[(wm + mi*16 + fm)*GK + fk];
#pragma unroll
    for (int ni=0; ni<4; ++ni)
      bfr[ni] = *(const bf16x8*)&Bls[(wn + ni*16 + fm)*GK + fk];
#pragma unroll
    for (int mi=0; mi<4; ++mi)
#pragma unroll
      for (int ni=0; ni<4; ++ni)
        acc[mi][ni] = __builtin_amdgcn_mfma_f32_16x16x32_bf16(af[mi], bfr[ni], acc[mi][ni], 0, 0, 0);
    __syncthreads();
  }

  int cn = lane & 15, cr = (lane >> 4) * 4;
#pragma unroll
  for (int ni=0; ni<4; ++ni){
    int col = col0 + wn + ni*16 + cn;
    float bb = bias[col];
#pragma unroll
    for (int mi=0; mi<4; ++mi){
#pragma unroll
      for (int r=0; r<4; ++r){
        int row = row0 + wm + mi*16 + cr + r;
        if (row < M){
          float v = acc[mi][ni][r] + bb;
          if (Cf) Cf[(size_t)row*256 + col] = v;
          else    Cb[(size_t)row*256 + col] = f2b(v);
        }
      }
    }
  }
}

// ---------------- CSR build by dst ----------------
__global__ void hist_kernel(const int* __restrict__ ei, int* __restrict__ deg){
  int e = blockIdx.x*blockDim.x + threadIdx.x;
  if (e < EE) atomicAdd(&deg[ei[EE + e]], 1);
}

__global__ void scan_kernel(const int* __restrict__ deg, int* __restrict__ rowptr, int* __restrict__ cursor){
  __shared__ int buf[1024];
  __shared__ int carry_s;
  int t = threadIdx.x;
  if (t == 0) carry_s = 0;
  __syncthreads();
  for (int base = 0; base < NN; base += 1024) {
    int i = base + t;
    int v = (i < NN) ? deg[i] : 0;
    buf[t] = v;
    __syncthreads();
    for (int off = 1; off < 1024; off <<= 1) {
      int other = (t >= off) ? buf[t - off] : 0;
      __syncthreads();
      buf[t] += other;
      __syncthreads();
    }
    int incl = buf[t];
    int carry = carry_s;
    if (i < NN) { int ex = carry + incl - v; rowptr[i] = ex; cursor[i] = ex; }
    __syncthreads();
    if (t == 1023) carry_s = carry + buf[1023];
    __syncthreads();
  }
  if (t == 0) rowptr[NN] = carry_s;
}

__global__ void scatter_kernel(const int* __restrict__ ei, int* __restrict__ cursor, int* __restrict__ eidx){
  int e = blockIdx.x*blockDim.x + threadIdx.x;
  if (e < EE) {
    int dst = ei[EE + e];
    int pos = atomicAdd(&cursor[dst], 1);
    eidx[pos] = e;
  }
}

// ---------------- per-node attention: single pass ----------------
// one wave per dst node; lane covers channels [4*lane, 4*lane+4)
// accumulates unnormalized sum + denom; writes raw ex into alpha buffer,
// denom to denom_buf; epilogue does LN/silu/residual, writes h in bf16.
__global__ __launch_bounds__(256) void node_attn_kernel(
    const int* __restrict__ ei, const float* __restrict__ kpts,
    const unsigned short* __restrict__ xl, const unsigned short* __restrict__ xr,
    const float* __restrict__ We, const float* __restrict__ att,
    const float* __restrict__ cbias, const float* __restrict__ gamma,
    const float* __restrict__ beta,
    const int* __restrict__ rowptr, const int* __restrict__ eidx,
    const float* __restrict__ identity,
    float* __restrict__ alpha_out, float* __restrict__ denom_buf,
    unsigned short* __restrict__ hbuf)
{
  int wid  = threadIdx.x >> 6;
  int lane = threadIdx.x & 63;
  int v = blockIdx.x*4 + wid;
  if (v >= NN) return;
  int c0 = lane*4;
  int head = lane >> 4;

  float4 we0 = ld4(We + c0);
  float4 we1 = ld4(We + 256 + c0);
  float4 we2 = ld4(We + 512 + c0);
  float4 av  = ld4(att + c0);
  ushort4 xrq = *(const ushort4*)(xr + (size_t)v*256 + c0);
  float xr0 = b2f(xrq.x), xr1 = b2f(xrq.y), xr2 = b2f(xrq.z), xr3 = b2f(xrq.w);
  float du = kpts[2*v]   * (1.0f/1216.0f);
  float dv = kpts[2*v+1] * (1.0f/352.0f);
  int rs = rowptr[v], re = rowptr[v+1];

  float denom = 0.f;
  float a0=0.f, a1=0.f, a2=0.f, a3=0.f;
  for (int idx = rs; idx < re; ++idx) {
    int e = eidx[idx];
    int s = ei[e];
    float su = kpts[2*s]   * (1.0f/1216.0f);
    float sv = kpts[2*s+1] * (1.0f/352.0f);
    float ru = du - su, rv = dv - sv;
    float dist = sqrtf(ru*ru + rv*rv);
    ushort4 xq = *(const ushort4*)(xl + (size_t)s*256 + c0);
    float x0 = b2f(xq.x), x1 = b2f(xq.y), x2 = b2f(xq.z), x3 = b2f(xq.w);
    float m0 = x0 + xr0 + ru*we0.x + rv*we1.x + dist*we2.x;
    float m1 = x1 + xr1 + ru*we0.y + rv*we1.y + dist*we2.y;
    float m2 = x2 + xr2 + ru*we0.z + rv*we1.z + dist*we2.z;
    float m3 = x3 + xr3 + ru*we0.w + rv*we1.w + dist*we2.w;
    m0 = (m0 >= 0.f) ? m0 : 0.2f*m0;
    m1 = (m1 >= 0.f) ? m1 : 0.2f*m1;
    m2 = (m2 >= 0.f) ? m2 : 0.2f*m2;
    m3 = (m3 >= 0.f) ? m3 : 0.2f*m3;
    float p = m0*av.x + m1*av.y + m2*av.z + m3*av.w;
    p += __shfl_xor(p, 1, 64);
    p += __shfl_xor(p, 2, 64);
    p += __shfl_xor(p, 4, 64);
    p += __shfl_xor(p, 8, 64);   // per-head logit, replicated in 16-lane group
    float exv = expf(p);         // unshifted softmax: logits bounded (~|p|<8)
    denom += exv;
    if ((lane & 15) == 0) alpha_out[(size_t)e*4 + head] = exv;  // raw ex; scaled later
    a0 += exv*x0; a1 += exv*x1; a2 += exv*x2; a3 += exv*x3;
  }
  float rdenom = 1.0f / (denom + 1e-16f);
  if ((lane & 15) == 0) denom_buf[(size_t)v*4 + head] = denom;

  a0 = a0*rdenom + cbias[c0];
  a1 = a1*rdenom + cbias[c0+1];
  a2 = a2*rdenom + cbias[c0+2];
  a3 = a3*rdenom + cbias[c0+3];

  float ps  = a0 + a1 + a2 + a3;
  float ps2 = a0*a0 + a1*a1 + a2*a2 + a3*a3;
#pragma unroll
  for (int off = 1; off < 64; off <<= 1) {
    ps  += __shfl_xor(ps,  off, 64);
    ps2 += __shfl_xor(ps2, off, 64);
  }
  float mu  = ps  * (1.0f/256.0f);
  float var = ps2 * (1.0f/256.0f) - mu*mu;
  float rstd = rsqrtf(var + 1e-5f);
  float4 g  = ld4(gamma + c0);
  float4 b  = ld4(beta  + c0);
  float4 idv = ld4(identity + (size_t)v*256 + c0);
  float y0 = (a0 - mu)*rstd*g.x + b.x;
  float y1 = (a1 - mu)*rstd*g.y + b.y;
  float y2 = (a2 - mu)*rstd*g.z + b.z;
  float y3 = (a3 - mu)*rstd*g.w + b.w;
  y0 = y0 / (1.0f + expf(-y0)) + idv.x;
  y1 = y1 / (1.0f + expf(-y1)) + idv.y;
  y2 = y2 / (1.0f + expf(-y2)) + idv.z;
  y3 = y3 / (1.0f + expf(-y3)) + idv.w;
  ushort4 hq; hq.x=f2b(y0); hq.y=f2b(y1); hq.z=f2b(y2); hq.w=f2b(y3);
  *(ushort4*)(hbuf + (size_t)v*256 + c0) = hq;
}

// ---------------- finalize alpha: alpha[e,h] = ex[e,h] / (denom[dst,h]+1e-16) ----------------
__global__ void alpha_fin_kernel(const int* __restrict__ ei, const float* __restrict__ denom_buf,
                                 float* __restrict__ alpha)
{
  int e = blockIdx.x*blockDim.x + threadIdx.x;
  if (e >= EE) return;
  int d = ei[EE + e];
  float4 dn = ld4(denom_buf + (size_t)d*4);
  float4 a = ld4(alpha + (size_t)e*4);
  a.x /= (dn.x + 1e-16f);
  a.y /= (dn.y + 1e-16f);
  a.z /= (dn.z + 1e-16f);
  a.w /= (dn.w + 1e-16f);
  *(float4*)(alpha + (size_t)e*4) = a;
}

extern "C" void kernel_launch(void* const* d_in, const int* in_sizes, int n_in,
                              void* d_out, int out_size, void* d_ws, size_t ws_size,
                              hipStream_t stream)
{
  const float* x      = (const float*)d_in[0];
  const float* kpts   = (const float*)d_in[1];
  const float* pts3d  = (const float*)d_in[2];
  const int*   ei     = (const int*)d_in[3];
  const float* W1     = (const float*)d_in[4];
  const float* b1     = (const float*)d_in[5];
  const float* W2     = (const float*)d_in[6];
  const float* b2     = (const float*)d_in[7];
  const float* Wres   = (const float*)d_in[8];
  const float* bres   = (const float*)d_in[9];
  const float* Wl     = (const float*)d_in[10];
  const float* bl     = (const float*)d_in[11];
  const float* Wr     = (const float*)d_in[12];
  const float* br     = (const float*)d_in[13];
  const float* We     = (const float*)d_in[14];
  const float* att    = (const float*)d_in[15];
  const float* cbias  = (const float*)d_in[16];
  const float* gamma  = (const float*)d_in[17];
  const float* beta   = (const float*)d_in[18];
  const float* Wp     = (const float*)d_in[19];
  const float* bp     = (const float*)d_in[20];

  float* out       = (float*)d_out;
  float* alpha_out = out + (size_t)NN*HIDC;

  // workspace layout (units: float elements) — ~165 MB total
  float* wsf = (float*)d_ws;
  float*          identity = wsf;                               // 12,800,000 f
  unsigned short* xl       = (unsigned short*)(wsf + 12800000); // 50048*256 us = 6,406,144 f
  unsigned short* xr       = (unsigned short*)(wsf + 19206144);
  unsigned short* nodex    = (unsigned short*)(wsf + 25612288); // 50048*320 us = 8,007,680 f
  unsigned short* hbuf     = (unsigned short*)(wsf + 33619968); // 50048*256 us
  unsigned short* wt       = (unsigned short*)(wsf + 40026112); // 311,296 us = 155,648 f
  float*          denomb   = wsf + 40181760;                    // 200,000 f
  int*            deg      = (int*)(wsf + 40381760);
  int*            rowptr   = deg + NN;
  int*            cursor   = rowptr + NN + 1;
  int*            eidx     = cursor + NN;

  unsigned short* wtres = wt;
  unsigned short* wtl   = wt + 81920;
  unsigned short* wtr   = wt + 163840;
  unsigned short* wtp   = wt + 245760;

  cvt_x_kernel<<<12500, 256, 0, stream>>>(x, nodex);
  node_mlp_kernel<<<(NN+255)/256, 256, 0, stream>>>(kpts, pts3d, W1, b1, W2, b2, nodex);
  cvt_w_kernel<<<1216, 256, 0, stream>>>(Wres, Wl, Wr, Wp, wt);

  dim3 ggrid(NPAD/128, 2);
  mfma_gemm_kernel<<<ggrid, 256, 0, stream>>>(nodex, wtres, bres, identity, nullptr, NN, INCH);
  mfma_gemm_kernel<<<ggrid, 256, 0, stream>>>(nodex, wtl,   bl,   nullptr, xl,      NN, INCH);
  mfma_gemm_kernel<<<ggrid, 256, 0, stream>>>(nodex, wtr,   br,   nullptr, xr,      NN, INCH);

  hipMemsetAsync(deg, 0, NN*sizeof(int), stream);
  hist_kernel<<<(EE+255)/256, 256, 0, stream>>>(ei, deg);
  scan_kernel<<<1, 1024, 0, stream>>>(deg, rowptr, cursor);
  scatter_kernel<<<(EE+255)/256, 256, 0, stream>>>(ei, cursor, eidx);

  node_attn_kernel<<<(NN+3)/4, 256, 0, stream>>>(ei, kpts, xl, xr, We, att,
                                                 cbias, gamma, beta,
                                                 rowptr, eidx, identity,
                                                 alpha_out, denomb, hbuf);
  alpha_fin_kernel<<<(EE+255)/256, 256, 0, stream>>>(ei, denomb, alpha_out);

  mfma_gemm_kernel<<<ggrid, 256, 0, stream>>>(hbuf, wtp, bp, out, nullptr, NN, HIDC);
}

// Round 3
// 598.386 us; speedup vs baseline: 2.0682x; 1.2198x over previous
//
#include <hip/hip_runtime.h>
#include <math.h>

#define NN 50000
#define NPAD 50048
#define EE 800000
#define HIDC 256
#define INCH 320

typedef __attribute__((ext_vector_type(8))) short bf16x8;
typedef __attribute__((ext_vector_type(4))) float f32x4;

static __device__ __forceinline__ float4 ld4(const float* p){ return *(const float4*)p; }

static __device__ __forceinline__ unsigned short f2b(float f){
  union { float f; unsigned u; } v; v.f = f;
  unsigned r = v.u + 0x7fffu + ((v.u >> 16) & 1u);
  return (unsigned short)(r >> 16);
}
static __device__ __forceinline__ float b2f(unsigned short u){
  union { unsigned u; float f; } v; v.u = ((unsigned)u) << 16; return v.f;
}
static __device__ __forceinline__ float rlane_f(float v, int l){
  return __uint_as_float(__builtin_amdgcn_readlane(__float_as_uint(v), l));
}
static __device__ __forceinline__ int rlane_i(int v, int l){
  return __builtin_amdgcn_readlane(v, l);
}

typedef const __attribute__((address_space(1))) unsigned int* gas_u32;
typedef __attribute__((address_space(3))) unsigned int* las_u32;
static __device__ __forceinline__ void gload_lds16(const void* g, void* l){
  __builtin_amdgcn_global_load_lds((gas_u32)g, (las_u32)l, 16, 0, 0);
}

// ---------------- convert x (fp32 50000x256) into node_x bf16 (NPAD x 320, cols 0..255) ----------------
__global__ void cvt_x_kernel(const float* __restrict__ x, unsigned short* __restrict__ nodex)
{
  int t = blockIdx.x*blockDim.x + threadIdx.x;
  int row = t >> 6;
  if (row >= NN) return;
  int c4 = (t & 63) * 4;
  float4 v = ld4(x + (size_t)row*256 + c4);
  ushort4 o;
  o.x = f2b(v.x); o.y = f2b(v.y); o.z = f2b(v.z); o.w = f2b(v.w);
  *(ushort4*)(nodex + (size_t)row*320 + c4) = o;
}

// ---------------- node positional MLP: writes bf16 into node_x cols 256..319 ----------------
__global__ void node_mlp_kernel(const float* __restrict__ kpts,
                                const float* __restrict__ pts3d,
                                const float* __restrict__ W1, const float* __restrict__ b1,
                                const float* __restrict__ W2, const float* __restrict__ b2,
                                unsigned short* __restrict__ nodex)
{
  int i = blockIdx.x*blockDim.x + threadIdx.x;
  if (i >= NN) return;
  float u = kpts[2*i]   * (1.0f/1216.0f);
  float v = kpts[2*i+1] * (1.0f/352.0f);
  float d = pts3d[3*i+2];
  float h[32];
#pragma unroll
  for (int j=0;j<32;++j){
    float t = u*W1[j] + v*W1[32+j] + d*W1[64+j] + b1[j];
    h[j] = t / (1.0f + expf(-t));   // silu
  }
  for (int o=0;o<64;o+=4){
    float s0=b2[o], s1=b2[o+1], s2=b2[o+2], s3=b2[o+3];
#pragma unroll
    for (int j=0;j<32;++j){
      float hj = h[j];
      const float* w = W2 + j*64 + o;
      s0 += hj*w[0]; s1 += hj*w[1]; s2 += hj*w[2]; s3 += hj*w[3];
    }
    ushort4 r; r.x=f2b(s0); r.y=f2b(s1); r.z=f2b(s2); r.w=f2b(s3);
    *(ushort4*)(nodex + (size_t)i*320 + 256 + o) = r;
  }
}

// ---------------- convert + transpose weights to bf16 N-major (K contiguous) + bias concat ----------------
// wt layout: [Wres_T 256x320][Wl_T 256x320][Wr_T 256x320][Wp_T 256x256]; biascat = [bres,bl,br]
__global__ void cvt_w_kernel(const float* __restrict__ Wres, const float* __restrict__ Wl,
                             const float* __restrict__ Wr,   const float* __restrict__ Wp,
                             const float* __restrict__ bres, const float* __restrict__ bl,
                             const float* __restrict__ br,
                             unsigned short* __restrict__ wt, float* __restrict__ biascat)
{
  int t = blockIdx.x*blockDim.x + threadIdx.x;   // 312064 threads
  if (t < 245760) {
    int which = t / 81920;
    int rem = t % 81920;
    int n = rem / 320, k = rem % 320;
    const float* W = (which == 0) ? Wres : (which == 1) ? Wl : Wr;
    wt[(size_t)which*81920 + rem] = f2b(W[(size_t)k*256 + n]);
  } else if (t < 311296) {
    int r = t - 245760;
    int n = r / 256, k = r % 256;
    wt[245760 + r] = f2b(Wp[(size_t)k*256 + n]);
  } else {
    int r = t - 311296;   // 0..767
    const float* src = (r < 256) ? bres : (r < 512) ? bl : br;
    biascat[r] = src[r & 255];
  }
}

// ---------------- bf16 MFMA GEMM: C(M,Nt) = A(M,K) @ BT(Nt,K)^T + bias ----------------
// 128x128 tile, BK=32. Column segments of 256 route to different outputs:
// seg0 -> Cf (fp32), seg1 -> Cx1 (bf16), seg2 -> Cx2 (bf16)
#define GK 32
__global__ __launch_bounds__(256) void mfma_gemm_kernel(
    const unsigned short* __restrict__ A,   // Mpad x K bf16 row-major
    const unsigned short* __restrict__ BT,  // Nt x K bf16 row-major
    const float* __restrict__ bias,         // Nt
    float* __restrict__ Cf,
    unsigned short* __restrict__ Cx1,
    unsigned short* __restrict__ Cx2,
    int M, int K)
{
  __shared__ unsigned short Als[128*GK];
  __shared__ unsigned short Bls[128*GK];
  int tid = threadIdx.x;
  int lane = tid & 63, wave = tid >> 6;
  int wm = (wave >> 1) * 64, wn = (wave & 1) * 64;
  int row0 = blockIdx.x * 128, col0 = blockIdx.y * 128;

  f32x4 acc[4][4];
#pragma unroll
  for (int i=0;i<4;++i)
#pragma unroll
    for (int j=0;j<4;++j){ acc[i][j].x=0.f; acc[i][j].y=0.f; acc[i][j].z=0.f; acc[i][j].w=0.f; }

  int fm = lane & 15;
  int fk = (lane >> 4) * 8;

  for (int k0 = 0; k0 < K; k0 += GK) {
#pragma unroll
    for (int it = 0; it < 2; ++it) {
      int seg = it*256 + tid;
      int r = seg >> 2, kb = (seg & 3) * 8;
      gload_lds16(A  + (size_t)(row0 + r)*K + k0 + kb, Als + (it*256 + wave*64)*8);
      gload_lds16(BT + (size_t)(col0 + r)*K + k0 + kb, Bls + (it*256 + wave*64)*8);
    }
    __syncthreads();

    bf16x8 af[4], bfr[4];
#pragma unroll
    for (int mi=0; mi<4; ++mi)
      af[mi] = *(const bf16x8*)&Als[(wm + mi*16 + fm)*GK + fk];
#pragma unroll
    for (int ni=0; ni<4; ++ni)
      bfr[ni] = *(const bf16x8*)&Bls[(wn + ni*16 + fm)*GK + fk];
#pragma unroll
    for (int mi=0; mi<4; ++mi)
#pragma unroll
      for (int ni=0; ni<4; ++ni)
        acc[mi][ni] = __builtin_amdgcn_mfma_f32_16x16x32_bf16(af[mi], bfr[ni], acc[mi][ni], 0, 0, 0);
    __syncthreads();
  }

  int seg = col0 >> 8;                 // 128-col blocks never straddle 256 boundaries
  int colbase = col0 - seg*256;
  int cn = lane & 15, cr = (lane >> 4) * 4;
#pragma unroll
  for (int ni=0; ni<4; ++ni){
    int gcol = col0 + wn + ni*16 + cn;
    int col  = colbase + wn + ni*16 + cn;
    float bb = bias[gcol];
#pragma unroll
    for (int mi=0; mi<4; ++mi){
#pragma unroll
      for (int r=0; r<4; ++r){
        int row = row0 + wm + mi*16 + cr + r;
        if (row < M){
          float v = acc[mi][ni][r] + bb;
          if (seg == 0)      Cf [(size_t)row*256 + col] = v;
          else if (seg == 1) Cx1[(size_t)row*256 + col] = f2b(v);
          else               Cx2[(size_t)row*256 + col] = f2b(v);
        }
      }
    }
  }
}

// ---------------- CSR build by dst ----------------
__global__ void hist_kernel(const int* __restrict__ ei, int* __restrict__ deg){
  int e = blockIdx.x*blockDim.x + threadIdx.x;
  if (e < EE) atomicAdd(&deg[ei[EE + e]], 1);
}

__global__ __launch_bounds__(1024) void scan_kernel(const int* __restrict__ deg,
                                                    int* __restrict__ rowptr, int* __restrict__ cursor){
  __shared__ int wsums[16];
  __shared__ int carry_s;
  int t = threadIdx.x, lane = t & 63, w = t >> 6;
  if (t == 0) carry_s = 0;
  __syncthreads();
  for (int base = 0; base < NN; base += 1024) {
    int i = base + t;
    int v = (i < NN) ? deg[i] : 0;
    int sc = v;
#pragma unroll
    for (int off = 1; off < 64; off <<= 1) {
      int o = __shfl_up(sc, off, 64);
      if (lane >= off) sc += o;
    }
    if (lane == 63) wsums[w] = sc;
    __syncthreads();
    if (w == 0) {
      int ws = (lane < 16) ? wsums[lane] : 0;
#pragma unroll
      for (int off = 1; off < 16; off <<= 1) {
        int o = __shfl_up(ws, off, 64);
        if (lane >= off) ws += o;
      }
      if (lane < 16) wsums[lane] = ws;   // inclusive scan of wave sums
    }
    __syncthreads();
    int waveoff = (w > 0) ? wsums[w-1] : 0;
    int carry = carry_s;
    if (i < NN) { int ex = carry + waveoff + sc - v; rowptr[i] = ex; cursor[i] = ex; }
    __syncthreads();
    if (t == 1023) carry_s = carry + wsums[15];
    __syncthreads();
  }
  if (t == 0) rowptr[NN] = carry_s;
}

__global__ void scatter_kernel(const int* __restrict__ ei, int* __restrict__ cursor, int* __restrict__ eidx){
  int e = blockIdx.x*blockDim.x + threadIdx.x;
  if (e < EE) {
    int dst = ei[EE + e];
    int pos = atomicAdd(&cursor[dst], 1);
    eidx[pos] = e;
  }
}

// ---------------- per-node attention: single pass, batch-parallel edge prep ----------------
// one wave per dst node; lane covers channels [4*lane, 4*lane+4)
__global__ __launch_bounds__(256) void node_attn_kernel(
    const int* __restrict__ ei, const float* __restrict__ kpts,
    const unsigned short* __restrict__ xl, const unsigned short* __restrict__ xr,
    const float* __restrict__ We, const float* __restrict__ att,
    const float* __restrict__ cbias, const float* __restrict__ gamma,
    const float* __restrict__ beta,
    const int* __restrict__ rowptr, const int* __restrict__ eidx,
    const float* __restrict__ identity,
    float* __restrict__ alpha_out, float* __restrict__ denom_buf,
    unsigned short* __restrict__ hbuf)
{
  int wid  = threadIdx.x >> 6;
  int lane = threadIdx.x & 63;
  int v = blockIdx.x*4 + wid;
  if (v >= NN) return;
  int c0 = lane*4;
  int head = lane >> 4;

  float4 we0 = ld4(We + c0);
  float4 we1 = ld4(We + 256 + c0);
  float4 we2 = ld4(We + 512 + c0);
  float4 av  = ld4(att + c0);
  ushort4 xrq = *(const ushort4*)(xr + (size_t)v*256 + c0);
  float xr0 = b2f(xrq.x), xr1 = b2f(xrq.y), xr2 = b2f(xrq.z), xr3 = b2f(xrq.w);
  float du = kpts[2*v]   * (1.0f/1216.0f);
  float dv = kpts[2*v+1] * (1.0f/352.0f);
  int rs = rowptr[v], re = rowptr[v+1];
  int deg = re - rs;

  float denom = 0.f;
  float a0=0.f, a1=0.f, a2=0.f, a3=0.f;

  for (int base = 0; base < deg; base += 64) {
    int cnt = min(64, deg - base);
    // ---- parallel phase: lane i preps edge base+i ----
    int e = 0, s = 0; float ru = 0.f, rv = 0.f, dist = 0.f;
    if (lane < cnt) {
      e = eidx[rs + base + lane];
      s = ei[e];
      float su = kpts[2*s]   * (1.0f/1216.0f);
      float sv = kpts[2*s+1] * (1.0f/352.0f);
      ru = du - su; rv = dv - sv;
      dist = sqrtf(ru*ru + rv*rv);
    }
    // ---- serial phase over edges, broadcast via readlane, prefetch xl row ----
    int s0j = rlane_i(s, 0);
    ushort4 xq = *(const ushort4*)(xl + (size_t)s0j*256 + c0);
    for (int j = 0; j < cnt; ++j) {
      ushort4 cur = xq;
      if (j + 1 < cnt) {
        int sn = rlane_i(s, j+1);
        xq = *(const ushort4*)(xl + (size_t)sn*256 + c0);
      }
      float ruj = rlane_f(ru, j);
      float rvj = rlane_f(rv, j);
      float dj  = rlane_f(dist, j);
      int   ej  = rlane_i(e, j);
      float x0 = b2f(cur.x), x1 = b2f(cur.y), x2 = b2f(cur.z), x3 = b2f(cur.w);
      float m0 = (x0 + xr0) + ruj*we0.x + rvj*we1.x + dj*we2.x;
      float m1 = (x1 + xr1) + ruj*we0.y + rvj*we1.y + dj*we2.y;
      float m2 = (x2 + xr2) + ruj*we0.z + rvj*we1.z + dj*we2.z;
      float m3 = (x3 + xr3) + ruj*we0.w + rvj*we1.w + dj*we2.w;
      m0 = fmaxf(m0, 0.2f*m0);   // leaky relu (slope 0.2)
      m1 = fmaxf(m1, 0.2f*m1);
      m2 = fmaxf(m2, 0.2f*m2);
      m3 = fmaxf(m3, 0.2f*m3);
      float p = m0*av.x + m1*av.y + m2*av.z + m3*av.w;
      p += __shfl_xor(p, 1, 64);
      p += __shfl_xor(p, 2, 64);
      p += __shfl_xor(p, 4, 64);
      p += __shfl_xor(p, 8, 64);     // per-head logit (replicated over 16-lane group)
      float exv = __expf(p);         // unshifted softmax: logits bounded
      denom += exv;
      if ((lane & 15) == 0) alpha_out[(size_t)ej*4 + head] = exv;  // raw ex; scaled later
      a0 += exv*x0; a1 += exv*x1; a2 += exv*x2; a3 += exv*x3;
    }
  }
  float rdenom = 1.0f / (denom + 1e-16f);
  if ((lane & 15) == 0) denom_buf[(size_t)v*4 + head] = denom;

  a0 = a0*rdenom + cbias[c0];
  a1 = a1*rdenom + cbias[c0+1];
  a2 = a2*rdenom + cbias[c0+2];
  a3 = a3*rdenom + cbias[c0+3];

  float ps  = a0 + a1 + a2 + a3;
  float ps2 = a0*a0 + a1*a1 + a2*a2 + a3*a3;
#pragma unroll
  for (int off = 1; off < 64; off <<= 1) {
    ps  += __shfl_xor(ps,  off, 64);
    ps2 += __shfl_xor(ps2, off, 64);
  }
  float mu  = ps  * (1.0f/256.0f);
  float var = ps2 * (1.0f/256.0f) - mu*mu;
  float rstd = rsqrtf(var + 1e-5f);
  float4 g  = ld4(gamma + c0);
  float4 b  = ld4(beta  + c0);
  float4 idv = ld4(identity + (size_t)v*256 + c0);
  float y0 = (a0 - mu)*rstd*g.x + b.x;
  float y1 = (a1 - mu)*rstd*g.y + b.y;
  float y2 = (a2 - mu)*rstd*g.z + b.z;
  float y3 = (a3 - mu)*rstd*g.w + b.w;
  y0 = y0 / (1.0f + __expf(-y0)) + idv.x;
  y1 = y1 / (1.0f + __expf(-y1)) + idv.y;
  y2 = y2 / (1.0f + __expf(-y2)) + idv.z;
  y3 = y3 / (1.0f + __expf(-y3)) + idv.w;
  ushort4 hq; hq.x=f2b(y0); hq.y=f2b(y1); hq.z=f2b(y2); hq.w=f2b(y3);
  *(ushort4*)(hbuf + (size_t)v*256 + c0) = hq;
}

// ---------------- finalize alpha: alpha[e,h] = ex[e,h] / (denom[dst,h]+1e-16) ----------------
__global__ void alpha_fin_kernel(const int* __restrict__ ei, const float* __restrict__ denom_buf,
                                 float* __restrict__ alpha)
{
  int e = blockIdx.x*blockDim.x + threadIdx.x;
  if (e >= EE) return;
  int d = ei[EE + e];
  float4 dn = ld4(denom_buf + (size_t)d*4);
  float4 a = ld4(alpha + (size_t)e*4);
  a.x /= (dn.x + 1e-16f);
  a.y /= (dn.y + 1e-16f);
  a.z /= (dn.z + 1e-16f);
  a.w /= (dn.w + 1e-16f);
  *(float4*)(alpha + (size_t)e*4) = a;
}

extern "C" void kernel_launch(void* const* d_in, const int* in_sizes, int n_in,
                              void* d_out, int out_size, void* d_ws, size_t ws_size,
                              hipStream_t stream)
{
  const float* x      = (const float*)d_in[0];
  const float* kpts   = (const float*)d_in[1];
  const float* pts3d  = (const float*)d_in[2];
  const int*   ei     = (const int*)d_in[3];
  const float* W1     = (const float*)d_in[4];
  const float* b1     = (const float*)d_in[5];
  const float* W2     = (const float*)d_in[6];
  const float* b2     = (const float*)d_in[7];
  const float* Wres   = (const float*)d_in[8];
  const float* bres   = (const float*)d_in[9];
  const float* Wl     = (const float*)d_in[10];
  const float* bl     = (const float*)d_in[11];
  const float* Wr     = (const float*)d_in[12];
  const float* br     = (const float*)d_in[13];
  const float* We     = (const float*)d_in[14];
  const float* att    = (const float*)d_in[15];
  const float* cbias  = (const float*)d_in[16];
  const float* gamma  = (const float*)d_in[17];
  const float* beta   = (const float*)d_in[18];
  const float* Wp     = (const float*)d_in[19];
  const float* bp     = (const float*)d_in[20];

  float* out       = (float*)d_out;
  float* alpha_out = out + (size_t)NN*HIDC;

  // workspace layout (units: float elements)
  float* wsf = (float*)d_ws;
  float*          identity = wsf;                               // 12,800,000 f
  unsigned short* xl       = (unsigned short*)(wsf + 12800000); // 50048*256 us = 6,406,144 f
  unsigned short* xr       = (unsigned short*)(wsf + 19206144);
  unsigned short* nodex    = (unsigned short*)(wsf + 25612288); // 50048*320 us = 8,007,680 f
  unsigned short* hbuf     = (unsigned short*)(wsf + 33619968); // 50048*256 us
  unsigned short* wt       = (unsigned short*)(wsf + 40026112); // 311,296 us = 155,648 f
  float*          biascat  = wsf + 40181760;                    // 768 f
  float*          denomb   = wsf + 40182528;                    // 200,000 f
  int*            deg      = (int*)(wsf + 40382528);
  int*            rowptr   = deg + NN;
  int*            cursor   = rowptr + NN + 1;
  int*            eidx     = cursor + NN;

  unsigned short* wtcat = wt;            // 768 x 320 (Wres_T | Wl_T | Wr_T)
  unsigned short* wtp   = wt + 245760;   // 256 x 256

  cvt_x_kernel<<<12500, 256, 0, stream>>>(x, nodex);
  node_mlp_kernel<<<(NN+255)/256, 256, 0, stream>>>(kpts, pts3d, W1, b1, W2, b2, nodex);
  cvt_w_kernel<<<1219, 256, 0, stream>>>(Wres, Wl, Wr, Wp, bres, bl, br, wt, biascat);

  hipMemsetAsync(deg, 0, NN*sizeof(int), stream);
  hist_kernel<<<(EE+255)/256, 256, 0, stream>>>(ei, deg);
  scan_kernel<<<1, 1024, 0, stream>>>(deg, rowptr, cursor);
  scatter_kernel<<<(EE+255)/256, 256, 0, stream>>>(ei, cursor, eidx);

  // fused triple GEMM: [identity | x_l | x_r] = nodex @ [Wres|Wl|Wr] + [bres|bl|br]
  dim3 g3(NPAD/128, 6);
  mfma_gemm_kernel<<<g3, 256, 0, stream>>>(nodex, wtcat, biascat, identity, xl, xr, NN, INCH);

  node_attn_kernel<<<(NN+3)/4, 256, 0, stream>>>(ei, kpts, xl, xr, We, att,
                                                 cbias, gamma, beta,
                                                 rowptr, eidx, identity,
                                                 alpha_out, denomb, hbuf);
  alpha_fin_kernel<<<(EE+255)/256, 256, 0, stream>>>(ei, denomb, alpha_out);

  dim3 g1(NPAD/128, 2);
  mfma_gemm_kernel<<<g1, 256, 0, stream>>>(hbuf, wtp, bp, out, nullptr, nullptr, NN, HIDC);
}

// Round 4
// 557.923 us; speedup vs baseline: 2.2182x; 1.0725x over previous
//
#include <hip/hip_runtime.h>
#include <math.h>

#define NN 50000
#define NPAD 50048
#define EE 800000
#define HIDC 256
#define INCH 320

typedef __attribute__((ext_vector_type(8))) short bf16x8;
typedef __attribute__((ext_vector_type(4))) float f32x4;
typedef __attribute__((ext_vector_type(2))) float f32x2;

static __device__ __forceinline__ float4 ld4(const float* p){ return *(const float4*)p; }

static __device__ __forceinline__ unsigned short f2b(float f){
  union { float f; unsigned u; } v; v.f = f;
  unsigned r = v.u + 0x7fffu + ((v.u >> 16) & 1u);
  return (unsigned short)(r >> 16);
}
static __device__ __forceinline__ float b2f(unsigned short u){
  union { unsigned u; float f; } v; v.u = ((unsigned)u) << 16; return v.f;
}
static __device__ __forceinline__ float rlane_f(float v, int l){
  return __uint_as_float(__builtin_amdgcn_readlane(__float_as_uint(v), l));
}
static __device__ __forceinline__ int rlane_i(int v, int l){
  return __builtin_amdgcn_readlane(v, l);
}
// unpack two bf16 packed in a u32 -> 2 floats (lo = .x, hi = .y)
static __device__ __forceinline__ f32x2 unpk(unsigned u){
  f32x2 r;
  r.x = __uint_as_float(u << 16);
  r.y = __uint_as_float(u & 0xffff0000u);
  return r;
}
static __device__ __forceinline__ f32x2 fma2(f32x2 a, f32x2 b, f32x2 c){
  return __builtin_elementwise_fma(a, b, c);
}
static __device__ __forceinline__ f32x2 max2(f32x2 a, f32x2 b){
  return __builtin_elementwise_max(a, b);
}
static __device__ __forceinline__ f32x2 set2(float v){ f32x2 r; r.x = v; r.y = v; return r; }

typedef const __attribute__((address_space(1))) unsigned int* gas_u32;
typedef __attribute__((address_space(3))) unsigned int* las_u32;
static __device__ __forceinline__ void gload_lds16(const void* g, void* l){
  __builtin_amdgcn_global_load_lds((gas_u32)g, (las_u32)l, 16, 0, 0);
}

// ---------------- convert x (fp32 50000x256) into node_x bf16 (NPAD x 320, cols 0..255) ----------------
__global__ void cvt_x_kernel(const float* __restrict__ x, unsigned short* __restrict__ nodex)
{
  int t = blockIdx.x*blockDim.x + threadIdx.x;
  int row = t >> 6;
  if (row >= NN) return;
  int c4 = (t & 63) * 4;
  float4 v = ld4(x + (size_t)row*256 + c4);
  ushort4 o;
  o.x = f2b(v.x); o.y = f2b(v.y); o.z = f2b(v.z); o.w = f2b(v.w);
  *(ushort4*)(nodex + (size_t)row*320 + c4) = o;
}

// ---------------- node positional MLP: writes bf16 into node_x cols 256..319 ----------------
__global__ void node_mlp_kernel(const float* __restrict__ kpts,
                                const float* __restrict__ pts3d,
                                const float* __restrict__ W1, const float* __restrict__ b1,
                                const float* __restrict__ W2, const float* __restrict__ b2,
                                unsigned short* __restrict__ nodex)
{
  int i = blockIdx.x*blockDim.x + threadIdx.x;
  if (i >= NN) return;
  float u = kpts[2*i]   * (1.0f/1216.0f);
  float v = kpts[2*i+1] * (1.0f/352.0f);
  float d = pts3d[3*i+2];
  float h[32];
#pragma unroll
  for (int j=0;j<32;++j){
    float t = u*W1[j] + v*W1[32+j] + d*W1[64+j] + b1[j];
    h[j] = t / (1.0f + __expf(-t));   // silu
  }
  for (int o=0;o<64;o+=4){
    float s0=b2[o], s1=b2[o+1], s2=b2[o+2], s3=b2[o+3];
#pragma unroll
    for (int j=0;j<32;++j){
      float hj = h[j];
      const float* w = W2 + j*64 + o;
      s0 += hj*w[0]; s1 += hj*w[1]; s2 += hj*w[2]; s3 += hj*w[3];
    }
    ushort4 r; r.x=f2b(s0); r.y=f2b(s1); r.z=f2b(s2); r.w=f2b(s3);
    *(ushort4*)(nodex + (size_t)i*320 + 256 + o) = r;
  }
}

// ---------------- convert + transpose weights to bf16 N-major (K contiguous) + bias concat ----------------
__global__ void cvt_w_kernel(const float* __restrict__ Wres, const float* __restrict__ Wl,
                             const float* __restrict__ Wr,   const float* __restrict__ Wp,
                             const float* __restrict__ bres, const float* __restrict__ bl,
                             const float* __restrict__ br,
                             unsigned short* __restrict__ wt, float* __restrict__ biascat)
{
  int t = blockIdx.x*blockDim.x + threadIdx.x;   // 312064 threads
  if (t < 245760) {
    int which = t / 81920;
    int rem = t % 81920;
    int n = rem / 320, k = rem % 320;
    const float* W = (which == 0) ? Wres : (which == 1) ? Wl : Wr;
    wt[(size_t)which*81920 + rem] = f2b(W[(size_t)k*256 + n]);
  } else if (t < 311296) {
    int r = t - 245760;
    int n = r / 256, k = r % 256;
    wt[245760 + r] = f2b(Wp[(size_t)k*256 + n]);
  } else {
    int r = t - 311296;   // 0..767
    const float* src = (r < 256) ? bres : (r < 512) ? bl : br;
    biascat[r] = src[r & 255];
  }
}

// ---------------- bf16 MFMA GEMM: C(M,Nt) = A(M,K) @ BT(Nt,K)^T + bias ----------------
#define GK 32
__global__ __launch_bounds__(256) void mfma_gemm_kernel(
    const unsigned short* __restrict__ A,
    const unsigned short* __restrict__ BT,
    const float* __restrict__ bias,
    float* __restrict__ Cf,
    unsigned short* __restrict__ Cx1,
    unsigned short* __restrict__ Cx2,
    int M, int K)
{
  __shared__ unsigned short Als[128*GK];
  __shared__ unsigned short Bls[128*GK];
  int tid = threadIdx.x;
  int lane = tid & 63, wave = tid >> 6;
  int wm = (wave >> 1) * 64, wn = (wave & 1) * 64;
  int row0 = blockIdx.x * 128, col0 = blockIdx.y * 128;

  f32x4 acc[4][4];
#pragma unroll
  for (int i=0;i<4;++i)
#pragma unroll
    for (int j=0;j<4;++j){ acc[i][j].x=0.f; acc[i][j].y=0.f; acc[i][j].z=0.f; acc[i][j].w=0.f; }

  int fm = lane & 15;
  int fk = (lane >> 4) * 8;

  for (int k0 = 0; k0 < K; k0 += GK) {
#pragma unroll
    for (int it = 0; it < 2; ++it) {
      int seg = it*256 + tid;
      int r = seg >> 2, kb = (seg & 3) * 8;
      gload_lds16(A  + (size_t)(row0 + r)*K + k0 + kb, Als + (it*256 + wave*64)*8);
      gload_lds16(BT + (size_t)(col0 + r)*K + k0 + kb, Bls + (it*256 + wave*64)*8);
    }
    __syncthreads();

    bf16x8 af[4], bfr[4];
#pragma unroll
    for (int mi=0; mi<4; ++mi)
      af[mi] = *(const bf16x8*)&Als[(wm + mi*16 + fm)*GK + fk];
#pragma unroll
    for (int ni=0; ni<4; ++ni)
      bfr[ni] = *(const bf16x8*)&Bls[(wn + ni*16 + fm)*GK + fk];
#pragma unroll
    for (int mi=0; mi<4; ++mi)
#pragma unroll
      for (int ni=0; ni<4; ++ni)
        acc[mi][ni] = __builtin_amdgcn_mfma_f32_16x16x32_bf16(af[mi], bfr[ni], acc[mi][ni], 0, 0, 0);
    __syncthreads();
  }

  int seg = col0 >> 8;
  int colbase = col0 - seg*256;
  int cn = lane & 15, cr = (lane >> 4) * 4;
#pragma unroll
  for (int ni=0; ni<4; ++ni){
    int gcol = col0 + wn + ni*16 + cn;
    int col  = colbase + wn + ni*16 + cn;
    float bb = bias[gcol];
#pragma unroll
    for (int mi=0; mi<4; ++mi){
#pragma unroll
      for (int r=0; r<4; ++r){
        int row = row0 + wm + mi*16 + cr + r;
        if (row < M){
          float v = acc[mi][ni][r] + bb;
          if (seg == 0)      Cf [(size_t)row*256 + col] = v;
          else if (seg == 1) Cx1[(size_t)row*256 + col] = f2b(v);
          else               Cx2[(size_t)row*256 + col] = f2b(v);
        }
      }
    }
  }
}

// ---------------- CSR build by dst ----------------
__global__ void hist_kernel(const int* __restrict__ ei, int* __restrict__ deg){
  int e = blockIdx.x*blockDim.x + threadIdx.x;
  if (e < EE) atomicAdd(&deg[ei[EE + e]], 1);
}

// parallel 3-phase scan
__global__ __launch_bounds__(1024) void scan1_kernel(const int* __restrict__ deg,
                                                     int* __restrict__ incl, int* __restrict__ bsum){
  __shared__ int wsums[16];
  int t = threadIdx.x, lane = t & 63, w = t >> 6;
  int i = blockIdx.x*1024 + t;
  int v = (i < NN) ? deg[i] : 0;
  int sc = v;
#pragma unroll
  for (int off = 1; off < 64; off <<= 1) {
    int o = __shfl_up(sc, off, 64);
    if (lane >= off) sc += o;
  }
  if (lane == 63) wsums[w] = sc;
  __syncthreads();
  if (w == 0) {
    int ws = (lane < 16) ? wsums[lane] : 0;
#pragma unroll
    for (int off = 1; off < 16; off <<= 1) {
      int o = __shfl_up(ws, off, 64);
      if (lane >= off) ws += o;
    }
    if (lane < 16) wsums[lane] = ws;
  }
  __syncthreads();
  int woff = (w > 0) ? wsums[w-1] : 0;
  if (i < NN) incl[i] = sc + woff;
  if (t == 1023) bsum[blockIdx.x] = woff + sc;
}

__global__ void scan2_kernel(int* __restrict__ bsum, int nblk){
  int lane = threadIdx.x;
  int v = (lane < nblk) ? bsum[lane] : 0;
#pragma unroll
  for (int off = 1; off < 64; off <<= 1) {
    int o = __shfl_up(v, off, 64);
    if (lane >= off) v += o;
  }
  if (lane < nblk) bsum[lane] = v;
}

__global__ __launch_bounds__(1024) void scan3_kernel(const int* __restrict__ incl,
                                                     const int* __restrict__ deg,
                                                     const int* __restrict__ bsum,
                                                     int* __restrict__ rowptr, int* __restrict__ cursor,
                                                     int nblk){
  int i = blockIdx.x*1024 + threadIdx.x;
  if (i < NN) {
    int b = blockIdx.x;
    int prev = (b > 0) ? bsum[b-1] : 0;
    int ex = prev + incl[i] - deg[i];
    rowptr[i] = ex;
    cursor[i] = ex;
  }
  if (i == 0) rowptr[NN] = bsum[nblk-1];
}

// scatter: place edge into its dst bin AND precompute edge geometry
__global__ void scatter_kernel(const int* __restrict__ ei, const float* __restrict__ kpts,
                               int* __restrict__ cursor,
                               float4* __restrict__ edata, int* __restrict__ eord){
  int e = blockIdx.x*blockDim.x + threadIdx.x;
  if (e >= EE) return;
  int s = ei[e];
  int d = ei[EE + e];
  int pos = atomicAdd(&cursor[d], 1);
  float su = kpts[2*s]   * (1.0f/1216.0f);
  float sv = kpts[2*s+1] * (1.0f/352.0f);
  float du = kpts[2*d]   * (1.0f/1216.0f);
  float dv = kpts[2*d+1] * (1.0f/352.0f);
  float ru = du - su, rv = dv - sv;
  float dist = sqrtf(ru*ru + rv*rv);
  float4 ed; ed.x = ru; ed.y = rv; ed.z = dist; ed.w = __int_as_float(s);
  edata[pos] = ed;
  eord[pos] = e;
}

// ---------------- per-node attention: batched 8-deep gather pipeline + packed fp32 ----------------
#define LOAD8(Q, B0)                                               \
  if ((B0) < cnt) {                                                \
    _Pragma("unroll")                                              \
    for (int t = 0; t < 8; ++t) {                                  \
      int sj = rlane_i(s, ((B0) + t) & 63);                        \
      Q[t] = *(const uint2*)(xlp + ((size_t)sj << 8));             \
    }                                                              \
  }

#define PROC8(Q, B0)                                               \
  _Pragma("unroll")                                                \
  for (int t = 0; t < 8; ++t) {                                    \
    int j = (B0) + t;                                              \
    if (j < cnt) {                                                 \
      float ruj = rlane_f(ed.x, j);                                \
      float rvj = rlane_f(ed.y, j);                                \
      float dj  = rlane_f(ed.z, j);                                \
      f32x2 x01 = unpk(Q[t].x), x23 = unpk(Q[t].y);                \
      f32x2 t01 = fma2(set2(ruj), we0a, xr01);                     \
      t01 = fma2(set2(rvj), we1a, t01);                            \
      t01 = fma2(set2(dj),  we2a, t01);                            \
      t01 = t01 + x01;                                             \
      f32x2 t23 = fma2(set2(ruj), we0b, xr23);                     \
      t23 = fma2(set2(rvj), we1b, t23);                            \
      t23 = fma2(set2(dj),  we2b, t23);                            \
      t23 = t23 + x23;                                             \
      t01 = max2(t01, t01*0.2f);                                   \
      t23 = max2(t23, t23*0.2f);                                   \
      f32x2 pd = t01*atta;                                         \
      pd = fma2(t23, attb, pd);                                    \
      float p = pd.x + pd.y;                                       \
      p += __shfl_xor(p, 1, 64);                                   \
      p += __shfl_xor(p, 2, 64);                                   \
      p += __shfl_xor(p, 4, 64);                                   \
      p += __shfl_xor(p, 8, 64);                                   \
      float exv = __expf(p);                                       \
      denom += exv;                                                \
      int ej = rlane_i(e, j);                                      \
      if ((lane & 15) == 0) alpha_out[(size_t)ej*4 + head] = exv;  \
      f32x2 ex2 = set2(exv);                                       \
      agg01 = fma2(ex2, x01, agg01);                               \
      agg23 = fma2(ex2, x23, agg23);                               \
    }                                                              \
  }

__global__ __launch_bounds__(256) void node_attn_kernel(
    const float4* __restrict__ edata, const int* __restrict__ eord,
    const unsigned short* __restrict__ xl, const unsigned short* __restrict__ xr,
    const float* __restrict__ We, const float* __restrict__ att,
    const float* __restrict__ cbias, const float* __restrict__ gamma,
    const float* __restrict__ beta,
    const int* __restrict__ rowptr,
    const float* __restrict__ identity,
    float* __restrict__ alpha_out, float* __restrict__ denom_buf,
    unsigned short* __restrict__ hbuf)
{
  int wid  = threadIdx.x >> 6;
  int lane = threadIdx.x & 63;
  int v = blockIdx.x*4 + wid;
  if (v >= NN) return;
  int c0 = lane*4;
  int head = lane >> 4;

  f32x2 we0a, we0b, we1a, we1b, we2a, we2b, atta, attb;
  we0a.x = We[c0];       we0a.y = We[c0+1];       we0b.x = We[c0+2];       we0b.y = We[c0+3];
  we1a.x = We[256+c0];   we1a.y = We[256+c0+1];   we1b.x = We[256+c0+2];   we1b.y = We[256+c0+3];
  we2a.x = We[512+c0];   we2a.y = We[512+c0+1];   we2b.x = We[512+c0+2];   we2b.y = We[512+c0+3];
  atta.x = att[c0];      atta.y = att[c0+1];      attb.x = att[c0+2];      attb.y = att[c0+3];
  uint2 xrq = *(const uint2*)(xr + (size_t)v*256 + c0);
  f32x2 xr01 = unpk(xrq.x), xr23 = unpk(xrq.y);
  const unsigned short* xlp = xl + c0;

  int rs = rowptr[v], re = rowptr[v+1];
  int deg = re - rs;

  float denom = 0.f;
  f32x2 agg01 = set2(0.f), agg23 = set2(0.f);

  for (int base = 0; base < deg; base += 64) {
    int cnt = min(64, deg - base);
    float4 ed; ed.x = 0.f; ed.y = 0.f; ed.z = 0.f; ed.w = __int_as_float(0);
    int e = 0;
    if (lane < cnt) {
      ed = edata[rs + base + lane];
      e  = eord [rs + base + lane];
    }
    int s = __float_as_int(ed.w);

    uint2 qa[8], qb[8];
    LOAD8(qa, 0);
    for (int b0 = 0; b0 < cnt; b0 += 16) {
      LOAD8(qb, b0 + 8);
      PROC8(qa, b0);
      LOAD8(qa, b0 + 16);
      PROC8(qb, b0 + 8);
    }
  }

  float rdenom = 1.0f / (denom + 1e-16f);
  if ((lane & 15) == 0) denom_buf[(size_t)v*4 + head] = denom;

  float a0 = agg01.x*rdenom + cbias[c0];
  float a1 = agg01.y*rdenom + cbias[c0+1];
  float a2 = agg23.x*rdenom + cbias[c0+2];
  float a3 = agg23.y*rdenom + cbias[c0+3];

  float ps  = a0 + a1 + a2 + a3;
  float ps2 = a0*a0 + a1*a1 + a2*a2 + a3*a3;
#pragma unroll
  for (int off = 1; off < 64; off <<= 1) {
    ps  += __shfl_xor(ps,  off, 64);
    ps2 += __shfl_xor(ps2, off, 64);
  }
  float mu  = ps  * (1.0f/256.0f);
  float var = ps2 * (1.0f/256.0f) - mu*mu;
  float rstd = rsqrtf(var + 1e-5f);
  float4 g  = ld4(gamma + c0);
  float4 b  = ld4(beta  + c0);
  float4 idv = ld4(identity + (size_t)v*256 + c0);
  float y0 = (a0 - mu)*rstd*g.x + b.x;
  float y1 = (a1 - mu)*rstd*g.y + b.y;
  float y2 = (a2 - mu)*rstd*g.z + b.z;
  float y3 = (a3 - mu)*rstd*g.w + b.w;
  y0 = y0 / (1.0f + __expf(-y0)) + idv.x;
  y1 = y1 / (1.0f + __expf(-y1)) + idv.y;
  y2 = y2 / (1.0f + __expf(-y2)) + idv.z;
  y3 = y3 / (1.0f + __expf(-y3)) + idv.w;
  ushort4 hq; hq.x=f2b(y0); hq.y=f2b(y1); hq.z=f2b(y2); hq.w=f2b(y3);
  *(ushort4*)(hbuf + (size_t)v*256 + c0) = hq;
}

// ---------------- finalize alpha: alpha[e,h] = ex[e,h] / (denom[dst,h]+1e-16) ----------------
__global__ void alpha_fin_kernel(const int* __restrict__ ei, const float* __restrict__ denom_buf,
                                 float* __restrict__ alpha)
{
  int e = blockIdx.x*blockDim.x + threadIdx.x;
  if (e >= EE) return;
  int d = ei[EE + e];
  float4 dn = ld4(denom_buf + (size_t)d*4);
  float4 a = ld4(alpha + (size_t)e*4);
  a.x /= (dn.x + 1e-16f);
  a.y /= (dn.y + 1e-16f);
  a.z /= (dn.z + 1e-16f);
  a.w /= (dn.w + 1e-16f);
  *(float4*)(alpha + (size_t)e*4) = a;
}

extern "C" void kernel_launch(void* const* d_in, const int* in_sizes, int n_in,
                              void* d_out, int out_size, void* d_ws, size_t ws_size,
                              hipStream_t stream)
{
  const float* x      = (const float*)d_in[0];
  const float* kpts   = (const float*)d_in[1];
  const float* pts3d  = (const float*)d_in[2];
  const int*   ei     = (const int*)d_in[3];
  const float* W1     = (const float*)d_in[4];
  const float* b1     = (const float*)d_in[5];
  const float* W2     = (const float*)d_in[6];
  const float* b2     = (const float*)d_in[7];
  const float* Wres   = (const float*)d_in[8];
  const float* bres   = (const float*)d_in[9];
  const float* Wl     = (const float*)d_in[10];
  const float* bl     = (const float*)d_in[11];
  const float* Wr     = (const float*)d_in[12];
  const float* br     = (const float*)d_in[13];
  const float* We     = (const float*)d_in[14];
  const float* att    = (const float*)d_in[15];
  const float* cbias  = (const float*)d_in[16];
  const float* gamma  = (const float*)d_in[17];
  const float* beta   = (const float*)d_in[18];
  const float* Wp     = (const float*)d_in[19];
  const float* bp     = (const float*)d_in[20];

  float* out       = (float*)d_out;
  float* alpha_out = out + (size_t)NN*HIDC;

  // workspace layout (units: float elements) — ~153 MB
  float* wsf = (float*)d_ws;
  float*          identity = wsf;                               // 12,800,000 f
  unsigned short* xl       = (unsigned short*)(wsf + 12800000); // 12,812,288 us
  unsigned short* xr       = (unsigned short*)(wsf + 19206144);
  unsigned short* nodex    = (unsigned short*)(wsf + 25612288); // 16,015,360 us
  unsigned short* hbuf     = (unsigned short*)(wsf + 25612288); // alias nodex (dead after gemm3)
  unsigned short* wt       = (unsigned short*)(wsf + 33619968); // 311,296 us
  float*          biascat  = wsf + 33775616;                    // 768 f
  float*          denomb   = wsf + 33776384;                    // 200,000 f
  float4*         edata    = (float4*)(wsf + 33976384);         // 800,000 float4
  int*            eord     = (int*)(wsf + 37176384);            // 800,000 i
  int*            incl     = (int*)(wsf + 37176384);            // alias eord (dead before scatter)
  int*            deg      = (int*)(wsf + 37976384);            // 50,000 i
  int*            rowptr   = (int*)(wsf + 38026384);            // 50,001 i
  int*            cursor   = (int*)(wsf + 38076385);            // 50,000 i
  int*            bsum     = (int*)(wsf + 38126385);            // 64 i

  unsigned short* wtcat = wt;            // 768 x 320 (Wres_T | Wl_T | Wr_T)
  unsigned short* wtp   = wt + 245760;   // 256 x 256

  cvt_x_kernel<<<12500, 256, 0, stream>>>(x, nodex);
  node_mlp_kernel<<<(NN+255)/256, 256, 0, stream>>>(kpts, pts3d, W1, b1, W2, b2, nodex);
  cvt_w_kernel<<<1219, 256, 0, stream>>>(Wres, Wl, Wr, Wp, bres, bl, br, wt, biascat);

  // fused triple GEMM: [identity | x_l | x_r] = nodex @ [Wres|Wl|Wr] + [bres|bl|br]
  dim3 g3(NPAD/128, 6);
  mfma_gemm_kernel<<<g3, 256, 0, stream>>>(nodex, wtcat, biascat, identity, xl, xr, NN, INCH);

  hipMemsetAsync(deg, 0, NN*sizeof(int), stream);
  hist_kernel<<<(EE+255)/256, 256, 0, stream>>>(ei, deg);
  int nblk = (NN + 1023) / 1024;   // 49
  scan1_kernel<<<nblk, 1024, 0, stream>>>(deg, incl, bsum);
  scan2_kernel<<<1, 64, 0, stream>>>(bsum, nblk);
  scan3_kernel<<<nblk, 1024, 0, stream>>>(incl, deg, bsum, rowptr, cursor, nblk);
  scatter_kernel<<<(EE+255)/256, 256, 0, stream>>>(ei, kpts, cursor, edata, eord);

  node_attn_kernel<<<(NN+3)/4, 256, 0, stream>>>(edata, eord, xl, xr, We, att,
                                                 cbias, gamma, beta,
                                                 rowptr, identity,
                                                 alpha_out, denomb, hbuf);
  alpha_fin_kernel<<<(EE+255)/256, 256, 0, stream>>>(ei, denomb, alpha_out);

  dim3 g1(NPAD/128, 2);
  mfma_gemm_kernel<<<g1, 256, 0, stream>>>(hbuf, wtp, bp, out, nullptr, nullptr, NN, HIDC);
}